// Round 1
// baseline (250.464 us; speedup 1.0000x reference)
//
#include <hip/hip_runtime.h>
#include <hip/hip_bf16.h>

#define S_LEN 2048
#define EMB 768
#define NH 12
#define HD 64

typedef __attribute__((ext_vector_type(8))) short short8;
typedef __attribute__((ext_vector_type(4))) float f32x4;

__device__ __forceinline__ short f2bf(float f) {
  union { float f; unsigned u; } v; v.f = f;
  unsigned r = v.u + 0x7FFFu + ((v.u >> 16) & 1u);
  return (short)(r >> 16);
}

__global__ void cvt_bf16(const float* __restrict__ src, short* __restrict__ dst, int n) {
  int i = (blockIdx.x * blockDim.x + threadIdx.x) * 4;
  if (i >= n) return;
  float4 v = *reinterpret_cast<const float4*>(src + i);
  short4 o;
  o.x = f2bf(v.x); o.y = f2bf(v.y); o.z = f2bf(v.z); o.w = f2bf(v.w);
  *reinterpret_cast<short4*>(dst + i) = o;
}

// NT GEMM: C[n][f] = sum_k A[n][k] * B[f][k].  A:[M][768] bf16, B:[N][768] bf16.
// MODE 0: QKV projection epilogue (N=2304, sections q/k/v of 768 each)
// MODE 1: out projection epilogue (N=768, add bias, f32 out)
template<int MODE>
__global__ __launch_bounds__(256)
void gemm_nt(const short* __restrict__ A, const short* __restrict__ B,
             float* __restrict__ outk, float* __restrict__ outv,
             short* __restrict__ qb, short* __restrict__ kb, short* __restrict__ vtb,
             float* __restrict__ outp, const float* __restrict__ bias) {
  const int K = EMB;
  __shared__ __align__(16) short As[128][72];
  __shared__ __align__(16) short Bs[128][72];
  int tid = threadIdx.x;
  int lane = tid & 63, wid = tid >> 6;
  int wm = wid >> 1, wn = wid & 1;      // 2x2 wave grid, each wave 64x64
  int r16 = lane & 15, g4 = lane >> 4;
  int m0 = blockIdx.y * 128, n0 = blockIdx.x * 128;
  f32x4 acc[4][4] = {};
  int arow[4], acol[4];
#pragma unroll
  for (int i = 0; i < 4; i++) { int g = i * 256 + tid; arow[i] = g >> 3; acol[i] = (g & 7) * 8; }

  for (int k0 = 0; k0 < K; k0 += 64) {
    short8 a_ld[4], b_ld[4];
#pragma unroll
    for (int i = 0; i < 4; i++) {
      a_ld[i] = *reinterpret_cast<const short8*>(A + (long)(m0 + arow[i]) * K + k0 + acol[i]);
      b_ld[i] = *reinterpret_cast<const short8*>(B + (long)(n0 + arow[i]) * K + k0 + acol[i]);
    }
    __syncthreads();
#pragma unroll
    for (int i = 0; i < 4; i++) {
      *reinterpret_cast<short8*>(&As[arow[i]][acol[i]]) = a_ld[i];
      *reinterpret_cast<short8*>(&Bs[arow[i]][acol[i]]) = b_ld[i];
    }
    __syncthreads();
#pragma unroll
    for (int s = 0; s < 2; s++) {
      short8 af[4], bf[4];
#pragma unroll
      for (int t = 0; t < 4; t++) {
        af[t] = *reinterpret_cast<const short8*>(&As[wm * 64 + t * 16 + r16][s * 32 + g4 * 8]);
        bf[t] = *reinterpret_cast<const short8*>(&Bs[wn * 64 + t * 16 + r16][s * 32 + g4 * 8]);
      }
#pragma unroll
      for (int mt = 0; mt < 4; mt++)
#pragma unroll
        for (int nt = 0; nt < 4; nt++)
          acc[mt][nt] = __builtin_amdgcn_mfma_f32_16x16x32_bf16(af[mt], bf[nt], acc[mt][nt], 0, 0, 0);
    }
  }

#pragma unroll
  for (int mt = 0; mt < 4; mt++) {
    int nbase = m0 + wm * 64 + mt * 16 + g4 * 4;
#pragma unroll
    for (int nt = 0; nt < 4; nt++) {
      int f = n0 + wn * 64 + nt * 16 + r16;
#pragma unroll
      for (int r = 0; r < 4; r++) {
        float c = acc[mt][nt][r];
        int nn = nbase + r;
        if (MODE == 0) {
          int b = nn >> 11, s = nn & 2047;
          int sec = f / EMB; int fh = f - sec * EMB;
          int h = fh >> 6, d = fh & 63;
          int idx = (((b * NH) + h) * S_LEN + s) * HD + d;
          if (sec == 0) qb[idx] = f2bf(c);
          else if (sec == 1) { outk[idx] = c; kb[idx] = f2bf(c); }
          else { outv[idx] = c; vtb[(((b * NH) + h) * HD + d) * S_LEN + s] = f2bf(c); }
        } else {
          outp[(long)nn * EMB + f] = c + bias[f];
        }
      }
    }
  }
}

// Flash attention, causal, no 1/sqrt(d) scaling (faithful to reference).
// Grid: (32 q-blocks of 64 rows, 24 bh). 4 waves/block, each wave independent: 16 q-rows.
__global__ __launch_bounds__(256)
void flash_attn(const short* __restrict__ qb, const short* __restrict__ kb,
                const short* __restrict__ vtb, short* __restrict__ mb) {
  int wid = threadIdx.x >> 6, lane = threadIdx.x & 63;
  int r16 = lane & 15, g4 = lane >> 4;
  int bh = blockIdx.y;
  int q0 = blockIdx.x * 64 + wid * 16;
  const short* qh = qb + (long)bh * S_LEN * HD;
  const short* kh = kb + (long)bh * S_LEN * HD;
  const short* vh = vtb + (long)bh * HD * S_LEN;
  __shared__ __align__(16) short P[4][16][40];

  short8 qf0 = *reinterpret_cast<const short8*>(qh + (q0 + r16) * HD + g4 * 8);
  short8 qf1 = *reinterpret_cast<const short8*>(qh + (q0 + r16) * HD + 32 + g4 * 8);

  float m[4], l[4];
  f32x4 oacc[4] = {};
#pragma unroll
  for (int r = 0; r < 4; r++) { m[r] = -1e30f; l[r] = 0.f; }

  int nkt = (q0 + 15) / 32 + 1;
  for (int kt = 0; kt < nkt; kt++) {
    int kr0 = kt * 32;
    f32x4 sc0 = {0.f, 0.f, 0.f, 0.f}, sc1 = {0.f, 0.f, 0.f, 0.f};
    const short* kp0 = kh + (kr0 + r16) * HD + g4 * 8;
    short8 k00 = *reinterpret_cast<const short8*>(kp0);
    short8 k01 = *reinterpret_cast<const short8*>(kp0 + 32);
    const short* kp1 = kp0 + 16 * HD;
    short8 k10 = *reinterpret_cast<const short8*>(kp1);
    short8 k11 = *reinterpret_cast<const short8*>(kp1 + 32);
    sc0 = __builtin_amdgcn_mfma_f32_16x16x32_bf16(qf0, k00, sc0, 0, 0, 0);
    sc0 = __builtin_amdgcn_mfma_f32_16x16x32_bf16(qf1, k01, sc0, 0, 0, 0);
    sc1 = __builtin_amdgcn_mfma_f32_16x16x32_bf16(qf0, k10, sc1, 0, 0, 0);
    sc1 = __builtin_amdgcn_mfma_f32_16x16x32_bf16(qf1, k11, sc1, 0, 0, 0);

    // causal mask: C row = q0 + g4*4 + r, col = kr0 (+16) + r16
#pragma unroll
    for (int r = 0; r < 4; r++) {
      int qr = q0 + g4 * 4 + r;
      if (kr0 + r16 > qr)      sc0[r] = -1e30f;
      if (kr0 + 16 + r16 > qr) sc1[r] = -1e30f;
    }
    // online softmax: reduce across the 16 lanes holding one row's 16 cols
    float tm[4], ts[4];
#pragma unroll
    for (int r = 0; r < 4; r++) tm[r] = fmaxf(sc0[r], sc1[r]);
#pragma unroll
    for (int off = 1; off < 16; off <<= 1)
#pragma unroll
      for (int r = 0; r < 4; r++) tm[r] = fmaxf(tm[r], __shfl_xor(tm[r], off, 16));
    float nm[4], sca[4];
#pragma unroll
    for (int r = 0; r < 4; r++) {
      nm[r] = fmaxf(m[r], tm[r]);
      sca[r] = expf(m[r] - nm[r]);
      sc0[r] = expf(sc0[r] - nm[r]);
      sc1[r] = expf(sc1[r] - nm[r]);
      ts[r] = sc0[r] + sc1[r];
    }
#pragma unroll
    for (int off = 1; off < 16; off <<= 1)
#pragma unroll
      for (int r = 0; r < 4; r++) ts[r] += __shfl_xor(ts[r], off, 16);
#pragma unroll
    for (int r = 0; r < 4; r++) {
      l[r] = l[r] * sca[r] + ts[r];
      m[r] = nm[r];
      oacc[0][r] *= sca[r]; oacc[1][r] *= sca[r];
      oacc[2][r] *= sca[r]; oacc[3][r] *= sca[r];
    }
    // P (C-layout) -> LDS -> A-fragment layout
#pragma unroll
    for (int r = 0; r < 4; r++) {
      P[wid][g4 * 4 + r][r16]      = f2bf(sc0[r]);
      P[wid][g4 * 4 + r][16 + r16] = f2bf(sc1[r]);
    }
    short8 pf = *reinterpret_cast<const short8*>(&P[wid][r16][g4 * 8]);
#pragma unroll
    for (int dt = 0; dt < 4; dt++) {
      short8 vf = *reinterpret_cast<const short8*>(vh + (dt * 16 + r16) * S_LEN + kr0 + g4 * 8);
      oacc[dt] = __builtin_amdgcn_mfma_f32_16x16x32_bf16(pf, vf, oacc[dt], 0, 0, 0);
    }
  }

  int b = bh / NH, h = bh % NH;
#pragma unroll
  for (int dt = 0; dt < 4; dt++)
#pragma unroll
    for (int r = 0; r < 4; r++) {
      int s = q0 + g4 * 4 + r;
      int d = dt * 16 + r16;
      mb[(long)(b * S_LEN + s) * EMB + h * HD + d] = f2bf(oacc[dt][r] / l[r]);
    }
}

extern "C" void kernel_launch(void* const* d_in, const int* in_sizes, int n_in,
                              void* d_out, int out_size, void* d_ws, size_t ws_size,
                              hipStream_t stream) {
  const float* x  = (const float*)d_in[0];
  const float* Wq = (const float*)d_in[1];
  const float* Wk = (const float*)d_in[2];
  const float* Wv = (const float*)d_in[3];
  const float* Wo = (const float*)d_in[4];
  const float* bo = (const float*)d_in[5];

  float* out  = (float*)d_out;
  float* outk = out + 3145728;
  float* outv = out + 6291456;

  short* ws  = (short*)d_ws;
  short* xb  = ws;                 // [4096][768]
  short* Wb  = xb + 3145728;       // [2304][768]  (Wq;Wk;Wv)
  short* Wob = Wb + 1769472;       // [768][768]
  short* qb  = Wob + 589824;       // [24][2048][64]
  short* kb  = qb + 3145728;       // [24][2048][64]
  short* vtb = kb + 3145728;       // [24][64][2048]  (V transposed per head)
  short* mb  = vtb + 3145728;      // [4096][768]    merged attn, bf16

  cvt_bf16<<<3072, 256, 0, stream>>>(x, xb, 3145728);
  cvt_bf16<<<576, 256, 0, stream>>>(Wq, Wb, 589824);
  cvt_bf16<<<576, 256, 0, stream>>>(Wk, Wb + 589824, 589824);
  cvt_bf16<<<576, 256, 0, stream>>>(Wv, Wb + 1179648, 589824);
  cvt_bf16<<<576, 256, 0, stream>>>(Wo, Wob, 589824);

  gemm_nt<0><<<dim3(18, 32), 256, 0, stream>>>(xb, Wb, outk, outv, qb, kb, vtb, nullptr, nullptr);
  flash_attn<<<dim3(32, 24), 256, 0, stream>>>(qb, kb, vtb, mb);
  gemm_nt<1><<<dim3(6, 32), 256, 0, stream>>>(mb, Wob, nullptr, nullptr, nullptr, nullptr, nullptr, out, bo);
}

// Round 2
// 228.278 us; speedup vs baseline: 1.0972x; 1.0972x over previous
//
#include <hip/hip_runtime.h>
#include <hip/hip_bf16.h>

#define S_LEN 2048
#define EMB 768
#define NH 12
#define HD 64
#define L2E 1.44269504088896340736f

typedef __attribute__((ext_vector_type(8))) short short8;
typedef __attribute__((ext_vector_type(4))) float f32x4;

__device__ __forceinline__ short f2bf(float f) {
  union { float f; unsigned u; } v; v.f = f;
  unsigned r = v.u + 0x7FFFu + ((v.u >> 16) & 1u);
  return (short)(r >> 16);
}

__device__ __forceinline__ unsigned pkbf(float a, float b) {
  unsigned r;
  asm("v_cvt_pk_bf16_f32 %0, %1, %2" : "=v"(r) : "v"(a), "v"(b));
  return r;  // low16 = bf16(a), high16 = bf16(b)
}

__global__ void cvt_bf16(const float* __restrict__ src, short* __restrict__ dst, int n) {
  int i = (blockIdx.x * blockDim.x + threadIdx.x) * 4;
  if (i >= n) return;
  float4 v = *reinterpret_cast<const float4*>(src + i);
  short4 o;
  o.x = f2bf(v.x); o.y = f2bf(v.y); o.z = f2bf(v.z); o.w = f2bf(v.w);
  *reinterpret_cast<short4*>(dst + i) = o;
}

// NT GEMM: C[n][f] = sum_k A[n][k] * B[f][k].
template<int MODE>
__global__ __launch_bounds__(256)
void gemm_nt(const short* __restrict__ A, const short* __restrict__ B,
             float* __restrict__ outk, float* __restrict__ outv,
             short* __restrict__ qb, short* __restrict__ kb, short* __restrict__ vtb,
             float* __restrict__ outp, const float* __restrict__ bias) {
  const int K = EMB;
  __shared__ __align__(16) short As[128][72];
  __shared__ __align__(16) short Bs[128][72];
  int tid = threadIdx.x;
  int lane = tid & 63, wid = tid >> 6;
  int wm = wid >> 1, wn = wid & 1;
  int r16 = lane & 15, g4 = lane >> 4;
  int m0 = blockIdx.y * 128, n0 = blockIdx.x * 128;
  f32x4 acc[4][4] = {};
  int arow[4], acol[4];
#pragma unroll
  for (int i = 0; i < 4; i++) { int g = i * 256 + tid; arow[i] = g >> 3; acol[i] = (g & 7) * 8; }

  for (int k0 = 0; k0 < K; k0 += 64) {
    short8 a_ld[4], b_ld[4];
#pragma unroll
    for (int i = 0; i < 4; i++) {
      a_ld[i] = *reinterpret_cast<const short8*>(A + (long)(m0 + arow[i]) * K + k0 + acol[i]);
      b_ld[i] = *reinterpret_cast<const short8*>(B + (long)(n0 + arow[i]) * K + k0 + acol[i]);
    }
    __syncthreads();
#pragma unroll
    for (int i = 0; i < 4; i++) {
      *reinterpret_cast<short8*>(&As[arow[i]][acol[i]]) = a_ld[i];
      *reinterpret_cast<short8*>(&Bs[arow[i]][acol[i]]) = b_ld[i];
    }
    __syncthreads();
#pragma unroll
    for (int s = 0; s < 2; s++) {
      short8 af[4], bf[4];
#pragma unroll
      for (int t = 0; t < 4; t++) {
        af[t] = *reinterpret_cast<const short8*>(&As[wm * 64 + t * 16 + r16][s * 32 + g4 * 8]);
        bf[t] = *reinterpret_cast<const short8*>(&Bs[wn * 64 + t * 16 + r16][s * 32 + g4 * 8]);
      }
#pragma unroll
      for (int mt = 0; mt < 4; mt++)
#pragma unroll
        for (int nt = 0; nt < 4; nt++)
          acc[mt][nt] = __builtin_amdgcn_mfma_f32_16x16x32_bf16(af[mt], bf[nt], acc[mt][nt], 0, 0, 0);
    }
  }

#pragma unroll
  for (int mt = 0; mt < 4; mt++) {
    int nbase = m0 + wm * 64 + mt * 16 + g4 * 4;
#pragma unroll
    for (int nt = 0; nt < 4; nt++) {
      int f = n0 + wn * 64 + nt * 16 + r16;
#pragma unroll
      for (int r = 0; r < 4; r++) {
        float c = acc[mt][nt][r];
        int nn = nbase + r;
        if (MODE == 0) {
          int b = nn >> 11, s = nn & 2047;
          int sec = f / EMB; int fh = f - sec * EMB;
          int h = fh >> 6, d = fh & 63;
          int idx = (((b * NH) + h) * S_LEN + s) * HD + d;
          if (sec == 0) qb[idx] = f2bf(c);
          else if (sec == 1) { outk[idx] = c; kb[idx] = f2bf(c); }
          else { outv[idx] = c; vtb[(((b * NH) + h) * HD + d) * S_LEN + s] = f2bf(c); }
        } else {
          outp[(long)nn * EMB + f] = c + bias[f];
        }
      }
    }
  }
}

// Flash attention with block-level split-KV.
// Block = (bh, 32-row q strip). 4 waves split the KV tile range; LDS merge.
// Swapped QK^T: sc = mfma(Kfrag, Qfrag) -> S^T[k][q]; row-reduce is register-axis.
__global__ __launch_bounds__(256)
void flash_attn2(const short* __restrict__ qb, const short* __restrict__ kb,
                 const short* __restrict__ vtb, short* __restrict__ mb) {
  const int tid = threadIdx.x;
  const int w = tid >> 6, lane = tid & 63;
  const int r16 = lane & 15, g4 = lane >> 4;
  const int bh = blockIdx.y;
  const int strip = 63 - blockIdx.x;          // longest strips dispatch first
  const int q0 = strip * 32;
  const int nkt = strip + 1;                  // 32-col KV tiles before+incl diagonal

  const short* qh = qb + (long)bh * S_LEN * HD;
  const short* kh = kb + (long)bh * S_LEN * HD;
  const short* vh = vtb + (long)bh * HD * S_LEN;

  __shared__ __align__(16) short P_lds[4][32][40];
  __shared__ __align__(16) float sca_lds[4][32];
  __shared__ float mlm[4][32], mll[4][32];
  __shared__ __align__(16) float wsc[4][32];
  __shared__ __align__(16) float o_lds[32][68];
  __shared__ float l_red[32];

  for (int i = tid; i < 32 * 68; i += 256) (&o_lds[0][0])[i] = 0.f;

  // Q fragments (B-side): lane holds Q[q = ct*16+r16][d = ksl*32 + g4*8 ..+7]
  short8 qf[2][2];
#pragma unroll
  for (int ct = 0; ct < 2; ct++)
#pragma unroll
    for (int ksl = 0; ksl < 2; ksl++)
      qf[ct][ksl] = *reinterpret_cast<const short8*>(qh + (q0 + ct * 16 + r16) * HD + ksl * 32 + g4 * 8);

  float m[2]  = {-1e30f, -1e30f};
  float m2[2] = {-1.44e30f, -1.44e30f};  // m * L2E
  float l[2]  = {0.f, 0.f};
  f32x4 oacc[2][4] = {};

  int base = nkt >> 2, rem = nkt & 3;
  int start = w * base + (w < rem ? w : rem);
  int count = base + (w < rem ? 1 : 0);

  for (int it = 0; it < count; it++) {
    int kt = start + it;
    int kr0 = kt * 32;

    // K fragments (A-side): lane holds K[k = mt*16+r16][d = ksl*32 + g4*8 ..+7]
    short8 kf[2][2];
#pragma unroll
    for (int mt = 0; mt < 2; mt++)
#pragma unroll
      for (int ksl = 0; ksl < 2; ksl++)
        kf[mt][ksl] = *reinterpret_cast<const short8*>(kh + (kr0 + mt * 16 + r16) * HD + ksl * 32 + g4 * 8);

    // S^T[k][q]: C row = k = mt*16 + g4*4 + r, col = q = ct*16 + r16
    f32x4 sc[2][2] = {};
#pragma unroll
    for (int mt = 0; mt < 2; mt++)
#pragma unroll
      for (int ct = 0; ct < 2; ct++) {
        sc[mt][ct] = __builtin_amdgcn_mfma_f32_16x16x32_bf16(kf[mt][0], qf[ct][0], sc[mt][ct], 0, 0, 0);
        sc[mt][ct] = __builtin_amdgcn_mfma_f32_16x16x32_bf16(kf[mt][1], qf[ct][1], sc[mt][ct], 0, 0, 0);
      }

    if (kt == nkt - 1) {  // diagonal tile: mask k > q
#pragma unroll
      for (int mt = 0; mt < 2; mt++)
#pragma unroll
        for (int ct = 0; ct < 2; ct++)
#pragma unroll
          for (int r = 0; r < 4; r++)
            if (mt * 16 + g4 * 4 + r > ct * 16 + r16) sc[mt][ct][r] = -1e30f;
    }

    // per-q row max: register-axis (8 vals) + 2 cross-lane combines
    float rm[2];
#pragma unroll
    for (int ct = 0; ct < 2; ct++) {
      float a = fmaxf(fmaxf(sc[0][ct][0], sc[0][ct][1]), fmaxf(sc[0][ct][2], sc[0][ct][3]));
      float b = fmaxf(fmaxf(sc[1][ct][0], sc[1][ct][1]), fmaxf(sc[1][ct][2], sc[1][ct][3]));
      float x = fmaxf(a, b);
      x = fmaxf(x, __shfl_xor(x, 16));
      x = fmaxf(x, __shfl_xor(x, 32));
      rm[ct] = x;
    }

    // defer-max: skip O-rescale when growth <= 8 for every row
    bool cond = (rm[0] <= m[0] + 8.f) && (rm[1] <= m[1] + 8.f);
    if (!__all(cond)) {
      float sca[2];
#pragma unroll
      for (int ct = 0; ct < 2; ct++) {
        float nm = fmaxf(m[ct], rm[ct]);
        sca[ct] = __builtin_exp2f((m[ct] - nm) * L2E);
        m[ct] = nm; m2[ct] = nm * L2E;
        l[ct] *= sca[ct];
      }
      if (g4 == 0) { sca_lds[w][r16] = sca[0]; sca_lds[w][16 + r16] = sca[1]; }
      f32x4 sr[2];
#pragma unroll
      for (int mt = 0; mt < 2; mt++)
        sr[mt] = *reinterpret_cast<const f32x4*>(&sca_lds[w][mt * 16 + g4 * 4]);
#pragma unroll
      for (int mt = 0; mt < 2; mt++)
#pragma unroll
        for (int dt = 0; dt < 4; dt++)
#pragma unroll
          for (int r = 0; r < 4; r++) oacc[mt][dt][r] *= sr[mt][r];
    }

    // P = exp2(sc*L2E - m2), row sums, pack to bf16, stage to LDS
    float p[2][2][4];
    float rs[2] = {0.f, 0.f};
#pragma unroll
    for (int mt = 0; mt < 2; mt++)
#pragma unroll
      for (int ct = 0; ct < 2; ct++)
#pragma unroll
        for (int r = 0; r < 4; r++) {
          float e = __builtin_exp2f(fmaf(sc[mt][ct][r], L2E, -m2[ct]));
          p[mt][ct][r] = e;
          rs[ct] += e;
        }
#pragma unroll
    for (int ct = 0; ct < 2; ct++) {
      float x = rs[ct];
      x += __shfl_xor(x, 16);
      x += __shfl_xor(x, 32);
      l[ct] += x;
    }
#pragma unroll
    for (int mt = 0; mt < 2; mt++)
#pragma unroll
      for (int ct = 0; ct < 2; ct++) {
        uint2 wv;
        wv.x = pkbf(p[mt][ct][0], p[mt][ct][1]);
        wv.y = pkbf(p[mt][ct][2], p[mt][ct][3]);
        *reinterpret_cast<uint2*>(&P_lds[w][ct * 16 + r16][mt * 16 + g4 * 4]) = wv;
      }

    // PV: A = P[q][k] (from LDS), B = Vt[d][k] (global), O[q][d]
    short8 pa[2];
#pragma unroll
    for (int mt = 0; mt < 2; mt++)
      pa[mt] = *reinterpret_cast<const short8*>(&P_lds[w][mt * 16 + r16][g4 * 8]);
#pragma unroll
    for (int dt = 0; dt < 4; dt++) {
      short8 vf = *reinterpret_cast<const short8*>(vh + (dt * 16 + r16) * S_LEN + kr0 + g4 * 8);
#pragma unroll
      for (int mt = 0; mt < 2; mt++)
        oacc[mt][dt] = __builtin_amdgcn_mfma_f32_16x16x32_bf16(pa[mt], vf, oacc[mt][dt], 0, 0, 0);
    }
  }

  // ---- block merge across the 4 KV-chunk waves ----
  if (g4 == 0) {
    mlm[w][r16] = m[0]; mll[w][r16] = l[0];
    mlm[w][16 + r16] = m[1]; mll[w][16 + r16] = l[1];
  }
  __syncthreads();
  if (tid < 32) {
    float M = fmaxf(fmaxf(mlm[0][tid], mlm[1][tid]), fmaxf(mlm[2][tid], mlm[3][tid]));
    float Ls = 0.f;
#pragma unroll
    for (int ww = 0; ww < 4; ww++) {
      float e = __builtin_exp2f((mlm[ww][tid] - M) * L2E);
      wsc[ww][tid] = e;
      Ls += e * mll[ww][tid];
    }
    l_red[tid] = Ls;
  }
  __syncthreads();
  {
    f32x4 fw[2];
#pragma unroll
    for (int mt = 0; mt < 2; mt++)
      fw[mt] = *reinterpret_cast<const f32x4*>(&wsc[w][mt * 16 + g4 * 4]);
#pragma unroll
    for (int mt = 0; mt < 2; mt++)
#pragma unroll
      for (int dt = 0; dt < 4; dt++)
#pragma unroll
        for (int r = 0; r < 4; r++)
          atomicAdd(&o_lds[mt * 16 + g4 * 4 + r][dt * 16 + r16], oacc[mt][dt][r] * fw[mt][r]);
  }
  __syncthreads();
  {
    int q = tid >> 3, db = (tid & 7) * 8;
    float inv = 1.f / l_red[q];
    f32x4 a = *reinterpret_cast<const f32x4*>(&o_lds[q][db]);
    f32x4 b = *reinterpret_cast<const f32x4*>(&o_lds[q][db + 4]);
    short8 o8;
#pragma unroll
    for (int j = 0; j < 4; j++) { o8[j] = f2bf(a[j] * inv); o8[4 + j] = f2bf(b[j] * inv); }
    int bb = bh / NH, h = bh % NH;
    *reinterpret_cast<short8*>(&mb[((long)(bb * S_LEN + q0 + q)) * EMB + h * HD + db]) = o8;
  }
}

extern "C" void kernel_launch(void* const* d_in, const int* in_sizes, int n_in,
                              void* d_out, int out_size, void* d_ws, size_t ws_size,
                              hipStream_t stream) {
  const float* x  = (const float*)d_in[0];
  const float* Wq = (const float*)d_in[1];
  const float* Wk = (const float*)d_in[2];
  const float* Wv = (const float*)d_in[3];
  const float* Wo = (const float*)d_in[4];
  const float* bo = (const float*)d_in[5];

  float* out  = (float*)d_out;
  float* outk = out + 3145728;
  float* outv = out + 6291456;

  short* ws  = (short*)d_ws;
  short* xb  = ws;                 // [4096][768]
  short* Wb  = xb + 3145728;       // [2304][768]  (Wq;Wk;Wv)
  short* Wob = Wb + 1769472;       // [768][768]
  short* qb  = Wob + 589824;       // [24][2048][64]
  short* kb  = qb + 3145728;       // [24][2048][64]
  short* vtb = kb + 3145728;       // [24][64][2048]  (V transposed per head)
  short* mb  = vtb + 3145728;      // [4096][768]    merged attn, bf16

  cvt_bf16<<<3072, 256, 0, stream>>>(x, xb, 3145728);
  cvt_bf16<<<576, 256, 0, stream>>>(Wq, Wb, 589824);
  cvt_bf16<<<576, 256, 0, stream>>>(Wk, Wb + 589824, 589824);
  cvt_bf16<<<576, 256, 0, stream>>>(Wv, Wb + 1179648, 589824);
  cvt_bf16<<<576, 256, 0, stream>>>(Wo, Wob, 589824);

  gemm_nt<0><<<dim3(18, 32), 256, 0, stream>>>(xb, Wb, outk, outv, qb, kb, vtb, nullptr, nullptr);
  flash_attn2<<<dim3(64, 24), 256, 0, stream>>>(qb, kb, vtb, mb);
  gemm_nt<1><<<dim3(6, 32), 256, 0, stream>>>(mb, Wob, nullptr, nullptr, nullptr, nullptr, nullptr, out, bo);
}

// Round 3
// 190.551 us; speedup vs baseline: 1.3144x; 1.1980x over previous
//
#include <hip/hip_runtime.h>
#include <hip/hip_bf16.h>

#define S_LEN 2048
#define EMB 768
#define NH 12
#define HD 64
#define L2E 1.44269504088896340736f

typedef __attribute__((ext_vector_type(8))) short short8;
typedef __attribute__((ext_vector_type(4))) float f32x4;

__device__ __forceinline__ short f2bf(float f) {
  union { float f; unsigned u; } v; v.f = f;
  unsigned r = v.u + 0x7FFFu + ((v.u >> 16) & 1u);
  return (short)(r >> 16);
}

__device__ __forceinline__ unsigned pkbf(float a, float b) {
  unsigned r;
  asm("v_cvt_pk_bf16_f32 %0, %1, %2" : "=v"(r) : "v"(a), "v"(b));
  return r;
}

__global__ void cvt_bf16(const float* __restrict__ src, short* __restrict__ dst, int n) {
  int i = (blockIdx.x * blockDim.x + threadIdx.x) * 4;
  if (i >= n) return;
  float4 v = *reinterpret_cast<const float4*>(src + i);
  short4 o;
  o.x = f2bf(v.x); o.y = f2bf(v.y); o.z = f2bf(v.z); o.w = f2bf(v.w);
  *reinterpret_cast<short4*>(dst + i) = o;
}

// fused weight converts: y = 0..3 selects Wq/Wk/Wv/Wo
__global__ void cvt_w(const float* __restrict__ Wq, const float* __restrict__ Wk,
                      const float* __restrict__ Wv, const float* __restrict__ Wo,
                      short* __restrict__ Wb, short* __restrict__ Wob) {
  int sec = blockIdx.y;
  const float* src = sec == 0 ? Wq : sec == 1 ? Wk : sec == 2 ? Wv : Wo;
  short* dst = sec < 3 ? Wb + sec * 589824 : Wob;
  int i = (blockIdx.x * blockDim.x + threadIdx.x) * 4;
  float4 v = *reinterpret_cast<const float4*>(src + i);
  short4 o;
  o.x = f2bf(v.x); o.y = f2bf(v.y); o.z = f2bf(v.z); o.w = f2bf(v.w);
  *reinterpret_cast<short4*>(dst + i) = o;
}

// NT GEMM: C[n][f] = sum_k A[n][k] * B[f][k].
template<int MODE>
__global__ __launch_bounds__(256)
void gemm_nt(const short* __restrict__ A, const short* __restrict__ B,
             float* __restrict__ outk, float* __restrict__ outv,
             short* __restrict__ qb, short* __restrict__ kb, short* __restrict__ vtb,
             float* __restrict__ outp, const float* __restrict__ bias) {
  const int K = EMB;
  __shared__ __align__(16) short As[128][72];
  __shared__ __align__(16) short Bs[128][72];
  int tid = threadIdx.x;
  int lane = tid & 63, wid = tid >> 6;
  int wm = wid >> 1, wn = wid & 1;
  int r16 = lane & 15, g4 = lane >> 4;
  int m0 = blockIdx.y * 128, n0 = blockIdx.x * 128;
  f32x4 acc[4][4] = {};
  int arow[4], acol[4];
#pragma unroll
  for (int i = 0; i < 4; i++) { int g = i * 256 + tid; arow[i] = g >> 3; acol[i] = (g & 7) * 8; }

  for (int k0 = 0; k0 < K; k0 += 64) {
    short8 a_ld[4], b_ld[4];
#pragma unroll
    for (int i = 0; i < 4; i++) {
      a_ld[i] = *reinterpret_cast<const short8*>(A + (long)(m0 + arow[i]) * K + k0 + acol[i]);
      b_ld[i] = *reinterpret_cast<const short8*>(B + (long)(n0 + arow[i]) * K + k0 + acol[i]);
    }
    __syncthreads();
#pragma unroll
    for (int i = 0; i < 4; i++) {
      *reinterpret_cast<short8*>(&As[arow[i]][acol[i]]) = a_ld[i];
      *reinterpret_cast<short8*>(&Bs[arow[i]][acol[i]]) = b_ld[i];
    }
    __syncthreads();
#pragma unroll
    for (int s = 0; s < 2; s++) {
      short8 af[4], bf[4];
#pragma unroll
      for (int t = 0; t < 4; t++) {
        af[t] = *reinterpret_cast<const short8*>(&As[wm * 64 + t * 16 + r16][s * 32 + g4 * 8]);
        bf[t] = *reinterpret_cast<const short8*>(&Bs[wn * 64 + t * 16 + r16][s * 32 + g4 * 8]);
      }
#pragma unroll
      for (int mt = 0; mt < 4; mt++)
#pragma unroll
        for (int nt = 0; nt < 4; nt++)
          acc[mt][nt] = __builtin_amdgcn_mfma_f32_16x16x32_bf16(af[mt], bf[nt], acc[mt][nt], 0, 0, 0);
    }
  }

#pragma unroll
  for (int mt = 0; mt < 4; mt++) {
    int nbase = m0 + wm * 64 + mt * 16 + g4 * 4;
#pragma unroll
    for (int nt = 0; nt < 4; nt++) {
      int f = n0 + wn * 64 + nt * 16 + r16;
#pragma unroll
      for (int r = 0; r < 4; r++) {
        float c = acc[mt][nt][r];
        int nn = nbase + r;
        if (MODE == 0) {
          int b = nn >> 11, s = nn & 2047;
          int sec = f / EMB; int fh = f - sec * EMB;
          int h = fh >> 6, d = fh & 63;
          int idx = (((b * NH) + h) * S_LEN + s) * HD + d;
          if (sec == 0) qb[idx] = f2bf(c);
          else if (sec == 1) { outk[idx] = c; kb[idx] = f2bf(c); }
          else { outv[idx] = c; vtb[(((b * NH) + h) * HD + d) * S_LEN + s] = f2bf(c); }
        } else {
          outp[(long)nn * EMB + f] = c + bias[f];
        }
      }
    }
  }
}

// Flash attention, block-level split-KV + XCD-affinity swizzle.
// Grid: 1536 1-D blocks. id&7 = XCD slot; each XCD group serves 3 bh so K/V
// (1.5 MB) stays resident in that XCD's 4 MB L2.
__global__ __launch_bounds__(256)
void flash_attn3(const short* __restrict__ qb, const short* __restrict__ kb,
                 const short* __restrict__ vtb, short* __restrict__ mb) {
  const int tid = threadIdx.x;
  const int w = tid >> 6, lane = tid & 63;
  const int r16 = lane & 15, g4 = lane >> 4;
  const int id = blockIdx.x;
  const int xcd = id & 7, j = id >> 3;
  const int bh = xcd + 8 * (j >> 6);
  const int strip = 63 - (j & 63);           // long strips first within group
  const int q0 = strip * 32;
  const int nkt = strip + 1;

  const short* qh = qb + (long)bh * S_LEN * HD;
  const short* kh = kb + (long)bh * S_LEN * HD;
  const short* vh = vtb + (long)bh * HD * S_LEN;

  __shared__ __align__(16) short P_lds[4][32][40];
  __shared__ __align__(16) float sca_lds[4][32];
  __shared__ float mlm[4][32], mll[4][32];
  __shared__ __align__(16) float wsc[4][32];
  __shared__ __align__(16) float o_lds[32][68];
  __shared__ float l_red[32];

  for (int i = tid; i < 32 * 68; i += 256) (&o_lds[0][0])[i] = 0.f;

  short8 qf[2][2];
#pragma unroll
  for (int ct = 0; ct < 2; ct++)
#pragma unroll
    for (int ksl = 0; ksl < 2; ksl++)
      qf[ct][ksl] = *reinterpret_cast<const short8*>(qh + (q0 + ct * 16 + r16) * HD + ksl * 32 + g4 * 8);

  float m[2]  = {-1e30f, -1e30f};
  float m2[2] = {-1.44e30f, -1.44e30f};
  float l[2]  = {0.f, 0.f};
  f32x4 oacc[2][4] = {};

  int base = nkt >> 2, rem = nkt & 3;
  int start = w * base + (w < rem ? w : rem);
  int count = base + (w < rem ? 1 : 0);

  for (int it = 0; it < count; it++) {
    int kt = start + it;
    int kr0 = kt * 32;

    // K fragments first, then V: QK^T's waitcnt leaves the 4 V loads in
    // flight through the softmax (counted-vmcnt style pipelining).
    short8 kf[2][2];
#pragma unroll
    for (int mt = 0; mt < 2; mt++)
#pragma unroll
      for (int ksl = 0; ksl < 2; ksl++)
        kf[mt][ksl] = *reinterpret_cast<const short8*>(kh + (kr0 + mt * 16 + r16) * HD + ksl * 32 + g4 * 8);
    short8 vf[4];
#pragma unroll
    for (int dt = 0; dt < 4; dt++)
      vf[dt] = *reinterpret_cast<const short8*>(vh + (dt * 16 + r16) * S_LEN + kr0 + g4 * 8);

    f32x4 sc[2][2] = {};
#pragma unroll
    for (int mt = 0; mt < 2; mt++)
#pragma unroll
      for (int ct = 0; ct < 2; ct++) {
        sc[mt][ct] = __builtin_amdgcn_mfma_f32_16x16x32_bf16(kf[mt][0], qf[ct][0], sc[mt][ct], 0, 0, 0);
        sc[mt][ct] = __builtin_amdgcn_mfma_f32_16x16x32_bf16(kf[mt][1], qf[ct][1], sc[mt][ct], 0, 0, 0);
      }

    if (kt == nkt - 1) {
#pragma unroll
      for (int mt = 0; mt < 2; mt++)
#pragma unroll
        for (int ct = 0; ct < 2; ct++)
#pragma unroll
          for (int r = 0; r < 4; r++)
            if (mt * 16 + g4 * 4 + r > ct * 16 + r16) sc[mt][ct][r] = -1e30f;
    }

    float rm[2];
#pragma unroll
    for (int ct = 0; ct < 2; ct++) {
      float a = fmaxf(fmaxf(sc[0][ct][0], sc[0][ct][1]), fmaxf(sc[0][ct][2], sc[0][ct][3]));
      float b = fmaxf(fmaxf(sc[1][ct][0], sc[1][ct][1]), fmaxf(sc[1][ct][2], sc[1][ct][3]));
      float x = fmaxf(a, b);
      x = fmaxf(x, __shfl_xor(x, 16));
      x = fmaxf(x, __shfl_xor(x, 32));
      rm[ct] = x;
    }

    bool cond = (rm[0] <= m[0] + 8.f) && (rm[1] <= m[1] + 8.f);
    if (!__all(cond)) {
      float sca[2];
#pragma unroll
      for (int ct = 0; ct < 2; ct++) {
        float nm = fmaxf(m[ct], rm[ct]);
        sca[ct] = __builtin_exp2f((m[ct] - nm) * L2E);
        m[ct] = nm; m2[ct] = nm * L2E;
        l[ct] *= sca[ct];
      }
      if (g4 == 0) { sca_lds[w][r16] = sca[0]; sca_lds[w][16 + r16] = sca[1]; }
      f32x4 sr[2];
#pragma unroll
      for (int mt = 0; mt < 2; mt++)
        sr[mt] = *reinterpret_cast<const f32x4*>(&sca_lds[w][mt * 16 + g4 * 4]);
#pragma unroll
      for (int mt = 0; mt < 2; mt++)
#pragma unroll
        for (int dt = 0; dt < 4; dt++)
#pragma unroll
          for (int r = 0; r < 4; r++) oacc[mt][dt][r] *= sr[mt][r];
    }

    float p[2][2][4];
    float rs[2] = {0.f, 0.f};
#pragma unroll
    for (int mt = 0; mt < 2; mt++)
#pragma unroll
      for (int ct = 0; ct < 2; ct++)
#pragma unroll
        for (int r = 0; r < 4; r++) {
          float e = __builtin_exp2f(fmaf(sc[mt][ct][r], L2E, -m2[ct]));
          p[mt][ct][r] = e;
          rs[ct] += e;
        }
#pragma unroll
    for (int ct = 0; ct < 2; ct++) {
      float x = rs[ct];
      x += __shfl_xor(x, 16);
      x += __shfl_xor(x, 32);
      l[ct] += x;
    }
#pragma unroll
    for (int mt = 0; mt < 2; mt++)
#pragma unroll
      for (int ct = 0; ct < 2; ct++) {
        uint2 wv;
        wv.x = pkbf(p[mt][ct][0], p[mt][ct][1]);
        wv.y = pkbf(p[mt][ct][2], p[mt][ct][3]);
        *reinterpret_cast<uint2*>(&P_lds[w][ct * 16 + r16][mt * 16 + g4 * 4]) = wv;
      }

    short8 pa[2];
#pragma unroll
    for (int mt = 0; mt < 2; mt++)
      pa[mt] = *reinterpret_cast<const short8*>(&P_lds[w][mt * 16 + r16][g4 * 8]);
#pragma unroll
    for (int dt = 0; dt < 4; dt++)
#pragma unroll
      for (int mt = 0; mt < 2; mt++)
        oacc[mt][dt] = __builtin_amdgcn_mfma_f32_16x16x32_bf16(pa[mt], vf[dt], oacc[mt][dt], 0, 0, 0);
  }

  if (g4 == 0) {
    mlm[w][r16] = m[0]; mll[w][r16] = l[0];
    mlm[w][16 + r16] = m[1]; mll[w][16 + r16] = l[1];
  }
  __syncthreads();
  if (tid < 32) {
    float M = fmaxf(fmaxf(mlm[0][tid], mlm[1][tid]), fmaxf(mlm[2][tid], mlm[3][tid]));
    float Ls = 0.f;
#pragma unroll
    for (int ww = 0; ww < 4; ww++) {
      float e = __builtin_exp2f((mlm[ww][tid] - M) * L2E);
      wsc[ww][tid] = e;
      Ls += e * mll[ww][tid];
    }
    l_red[tid] = Ls;
  }
  __syncthreads();
  {
    f32x4 fw[2];
#pragma unroll
    for (int mt = 0; mt < 2; mt++)
      fw[mt] = *reinterpret_cast<const f32x4*>(&wsc[w][mt * 16 + g4 * 4]);
#pragma unroll
    for (int mt = 0; mt < 2; mt++)
#pragma unroll
      for (int dt = 0; dt < 4; dt++)
#pragma unroll
        for (int r = 0; r < 4; r++)
          atomicAdd(&o_lds[mt * 16 + g4 * 4 + r][dt * 16 + r16], oacc[mt][dt][r] * fw[mt][r]);
  }
  __syncthreads();
  {
    int q = tid >> 3, db = (tid & 7) * 8;
    float inv = 1.f / l_red[q];
    f32x4 a = *reinterpret_cast<const f32x4*>(&o_lds[q][db]);
    f32x4 b = *reinterpret_cast<const f32x4*>(&o_lds[q][db + 4]);
    short8 o8;
#pragma unroll
    for (int jj = 0; jj < 4; jj++) { o8[jj] = f2bf(a[jj] * inv); o8[4 + jj] = f2bf(b[jj] * inv); }
    int bb = bh / NH, h = bh % NH;
    *reinterpret_cast<short8*>(&mb[((long)(bb * S_LEN + q0 + q)) * EMB + h * HD + db]) = o8;
  }
}

extern "C" void kernel_launch(void* const* d_in, const int* in_sizes, int n_in,
                              void* d_out, int out_size, void* d_ws, size_t ws_size,
                              hipStream_t stream) {
  const float* x  = (const float*)d_in[0];
  const float* Wq = (const float*)d_in[1];
  const float* Wk = (const float*)d_in[2];
  const float* Wv = (const float*)d_in[3];
  const float* Wo = (const float*)d_in[4];
  const float* bo = (const float*)d_in[5];

  float* out  = (float*)d_out;
  float* outk = out + 3145728;
  float* outv = out + 6291456;

  short* ws  = (short*)d_ws;
  short* xb  = ws;                 // [4096][768]
  short* Wb  = xb + 3145728;       // [2304][768]  (Wq;Wk;Wv)
  short* Wob = Wb + 1769472;       // [768][768]
  short* qb  = Wob + 589824;       // [24][2048][64]
  short* kb  = qb + 3145728;       // [24][2048][64]
  short* vtb = kb + 3145728;       // [24][64][2048]  (V transposed per head)
  short* mb  = vtb + 3145728;      // [4096][768]    merged attn, bf16

  cvt_bf16<<<3072, 256, 0, stream>>>(x, xb, 3145728);
  cvt_w<<<dim3(576, 4), 256, 0, stream>>>(Wq, Wk, Wv, Wo, Wb, Wob);

  gemm_nt<0><<<dim3(18, 32), 256, 0, stream>>>(xb, Wb, outk, outv, qb, kb, vtb, nullptr, nullptr);
  flash_attn3<<<1536, 256, 0, stream>>>(qb, kb, vtb, mb);
  gemm_nt<1><<<dim3(6, 32), 256, 0, stream>>>(mb, Wob, nullptr, nullptr, nullptr, nullptr, nullptr, out, bo);
}